// Round 14
// baseline (325.847 us; speedup 1.0000x reference)
//
#include <hip/hip_runtime.h>

#define F 64
typedef unsigned int u32;
typedef unsigned long long u64;
typedef float f8 __attribute__((ext_vector_type(8)));

#define SCAN_BLOCK 1024
#define SCAN_ITEMS 4   // elements per thread -> 4096 per block
#define NPART 8        // node partitions
#define EGRP 32        // edge groups per partition (grid = 256)
#define SLICE_MAX 12544

// ---- bf16x2 pack/unpack (RNE) ----------------------------------------------
__device__ __forceinline__ u32 pack_bf16x2(float lo, float hi) {
    u32 a = __float_as_uint(lo);
    u32 b = __float_as_uint(hi);
    a = (a + 0x7fffu + ((a >> 16) & 1u)) >> 16;
    b = (b + 0x7fffu + ((b >> 16) & 1u)) >> 16;
    return a | (b << 16);
}
__device__ __forceinline__ float unpack_lo(u32 p) { return __uint_as_float(p << 16); }
__device__ __forceinline__ float unpack_hi(u32 p) { return __uint_as_float(p & 0xffff0000u); }

// ---------------------------------------------------------------------------
// k_gemm: LDS-tiled GEMMs (unchanged; now launched AFTER the CSR build since
// staging aliases the x1p region).
// ---------------------------------------------------------------------------
__global__ __launch_bounds__(256, 4) void k_gemm(
    const float* __restrict__ x_real, const float* __restrict__ x_imag,
    const float* __restrict__ weight, const float* __restrict__ bias,
    u32* __restrict__ x1p, u32* __restrict__ initp, int n_nodes)
{
    __shared__ float xs[2][64 * 65];

    const int t = threadIdx.x;
    const int base_node = blockIdx.x * 64;

#pragma unroll
    for (int c = 0; c < 8; ++c) {
        const int fq  = t + 256 * c;
        const int arr = fq >> 10;
        const int rem = fq & 1023;
        const int n   = rem >> 4;
        const int c4  = rem & 15;
        const int g   = base_node + n;
        const float* __restrict__ s = arr ? x_imag : x_real;
        float4 v = make_float4(0.f, 0.f, 0.f, 0.f);
        if (g < n_nodes) v = *(const float4*)(s + (size_t)g * F + c4 * 4);
        float* d = &xs[arr][n * 65 + c4 * 4];
        d[0] = v.x; d[1] = v.y; d[2] = v.z; d[3] = v.w;
    }
    __syncthreads();

    const int lane = t & 63;
    const int f0 = __builtin_amdgcn_readfirstlane((t >> 6) * 16);
    const int g = base_node + lane;

    const float* __restrict__ W0 = weight;
    const float* __restrict__ W1 = weight + F * F;

    float aR0[16], aI0[16], aR1[16], aI1[16];
#pragma unroll
    for (int j = 0; j < 16; ++j) { aR0[j] = 0.f; aI0[j] = 0.f; aR1[j] = 0.f; aI1[j] = 0.f; }

    const float* __restrict__ xrow_r = &xs[0][lane * 65];
    const float* __restrict__ xrow_i = &xs[1][lane * 65];

    for (int k0 = 0; k0 < F; k0 += 4) {
#pragma unroll
        for (int kk = 0; kk < 4; ++kk) {
            const int k = k0 + kk;
            const float xr = xrow_r[k];
            const float xi = xrow_i[k];
            const f8 wa0 = *(const f8*)(W0 + k * F + f0);
            const f8 wb0 = *(const f8*)(W0 + k * F + f0 + 8);
            const f8 wa1 = *(const f8*)(W1 + k * F + f0);
            const f8 wb1 = *(const f8*)(W1 + k * F + f0 + 8);
#pragma unroll
            for (int j = 0; j < 8; ++j) {
                aR0[j]     = fmaf(xr, wa0[j], aR0[j]);
                aI0[j]     = fmaf(xi, wa0[j], aI0[j]);
                aR1[j]     = fmaf(xr, wa1[j], aR1[j]);
                aI1[j]     = fmaf(xi, wa1[j], aI1[j]);
                aR0[8 + j] = fmaf(xr, wb0[j], aR0[8 + j]);
                aI0[8 + j] = fmaf(xi, wb0[j], aI0[8 + j]);
                aR1[8 + j] = fmaf(xr, wb1[j], aR1[8 + j]);
                aI1[8 + j] = fmaf(xi, wb1[j], aI1[8 + j]);
            }
        }
    }

    if (g < n_nodes) {
        const f8 b0 = *(const f8*)(bias + f0);
        const f8 b1 = *(const f8*)(bias + f0 + 8);
        u32 pi[16], pw[16];
#pragma unroll
        for (int j = 0; j < 8; ++j) {
            pi[j]     = pack_bf16x2(aR0[j] + b0[j],     aI0[j] + b0[j]);
            pi[8 + j] = pack_bf16x2(aR0[8 + j] + b1[j], aI0[8 + j] + b1[j]);
            pw[j]     = pack_bf16x2(aR1[j],     aI1[j]);
            pw[8 + j] = pack_bf16x2(aR1[8 + j], aI1[8 + j]);
        }
        uint4* __restrict__ di = (uint4*)(initp + (size_t)g * F + f0);
        uint4* __restrict__ dw = (uint4*)(x1p  + (size_t)g * F + f0);
#pragma unroll
        for (int q = 0; q < 4; ++q) {
            di[q] = make_uint4(pi[4 * q], pi[4 * q + 1], pi[4 * q + 2], pi[4 * q + 3]);
            dw[q] = make_uint4(pw[4 * q], pw[4 * q + 1], pw[4 * q + 2], pw[4 * q + 3]);
        }
    }
}

// ---------------------------------------------------------------------------
// k_coarse: per-partition edge counts (8 LDS counters, 8 global atomics/blk).
// ---------------------------------------------------------------------------
__global__ __launch_bounds__(256) void k_coarse(
    const int* __restrict__ src, int* __restrict__ pcnt, int n_edges, int slice)
{
    __shared__ int c[NPART];
    const int t = threadIdx.x;
    if (t < NPART) c[t] = 0;
    __syncthreads();
    const int tid = blockIdx.x * 256 + t;
    const int stride = gridDim.x * 256;
    for (int e = tid; e < n_edges; e += stride)
        atomicAdd(&c[src[e] / slice], 1);
    __syncthreads();
    if (t < NPART && c[t] > 0) atomicAdd(&pcnt[t], c[t]);
}

// k_base: exclusive scan of 8 counts -> pbase[9], pcur[8].
__global__ __launch_bounds__(64) void k_base(
    const int* __restrict__ pcnt, int* __restrict__ pbase, int* __restrict__ pcur)
{
    const int t = threadIdx.x;
    int v = (t < NPART) ? pcnt[t] : 0;
    int incl = v;
#pragma unroll
    for (int d = 1; d < NPART; d <<= 1) {
        int x = __shfl_up(incl, d);
        if (t >= d) incl += x;
    }
    if (t < NPART) {
        pbase[t] = incl - v;
        pcur[t]  = incl - v;
    }
    if (t == NPART - 1) pbase[NPART] = incl;
}

// ---------------------------------------------------------------------------
// k_split: ONE pass over edges. Per 256-edge round: LDS-classify by partition,
// one chunk atomic per (round, partition), write (src, dst|norms) to the
// partition's staging region. Re-scan factor NPART -> 1.
// ---------------------------------------------------------------------------
__global__ __launch_bounds__(256) void k_split(
    const int* __restrict__ ei, const float* __restrict__ nr, const float* __restrict__ ni,
    int* __restrict__ pcur, u32* __restrict__ ssrc, u64* __restrict__ smrec,
    int n_edges, int slice, int chunk)
{
    __shared__ int cnt[NPART];
    __shared__ int gb[NPART];
    const int t = threadIdx.x;
    const int cbeg = blockIdx.x * chunk;
    const int cend = min(cbeg + chunk, n_edges);

    for (int base = cbeg; base < cend; base += 256) {
        if (t < NPART) cnt[t] = 0;
        __syncthreads();
        const int e = base + t;
        const bool valid = e < cend;
        int p = 0, lpos = 0;
        u32 s = 0; u64 mrec = 0;
        if (valid) {
            s = (u32)ei[e];
            const u32 d = (u32)ei[n_edges + e];
            const u32 nn = pack_bf16x2(nr[e], ni[e]);
            mrec = (u64)d | ((u64)nn << 32);
            p = (int)(s / (u32)slice);
            lpos = atomicAdd(&cnt[p], 1);
        }
        __syncthreads();
        if (t < NPART && cnt[t] > 0) gb[t] = atomicAdd(&pcur[t], cnt[t]);
        __syncthreads();
        if (valid) {
            const int gi = gb[p] + lpos;
            ssrc[gi]  = s;
            smrec[gi] = mrec;
        }
        __syncthreads();
    }
}

// ---------------------------------------------------------------------------
// k_hist8: per (part, grp): LDS histogram of the staged src range (dense,
// partition-local, no predicate) -> priv[grp][node]. Zero global atomics.
// ---------------------------------------------------------------------------
__global__ __launch_bounds__(1024) void k_hist8(
    const u32* __restrict__ ssrc, const int* __restrict__ pbase,
    int* __restrict__ priv, int n_nodes, int slice)
{
    __shared__ int h[SLICE_MAX];
    const int p = blockIdx.x & (NPART - 1);
    const int g = blockIdx.x >> 3;
    const int t = threadIdx.x;

    const int lo = p * slice;
    const int hi = min(lo + slice, n_nodes);
    const int sl = hi - lo;
    if (sl <= 0) return;

    for (int i = t; i < sl; i += 1024) h[i] = 0;
    __syncthreads();

    const int pb = pbase[p], pe = pbase[p + 1];
    const long long len = pe - pb;
    const int beg = pb + (int)(len * g / EGRP);
    const int end = pb + (int)(len * (g + 1) / EGRP);
    for (int e = beg + t; e < end; e += 1024)
        atomicAdd(&h[(int)ssrc[e] - lo], 1);
    __syncthreads();

    int* __restrict__ dst = priv + (size_t)g * n_nodes + lo;
    for (int i = t; i < sl; i += 1024) dst[i] = h[i];
}

// ---------------------------------------------------------------------------
// Scan pass 1: per-node count = sum_g priv[g][node]; block-local prefix.
// ---------------------------------------------------------------------------
__global__ __launch_bounds__(1024) void k_scan1(
    const int* __restrict__ priv, int* __restrict__ pre,
    int* __restrict__ partials, int n, int n_nodes)
{
    __shared__ int wsum[16];
    const int t = threadIdx.x;
    const int lane = t & 63, wid = t >> 6;
    const int base = blockIdx.x * (SCAN_BLOCK * SCAN_ITEMS) + t * SCAN_ITEMS;

    int v[SCAN_ITEMS];
    int local = 0;
#pragma unroll
    for (int j = 0; j < SCAN_ITEMS; ++j) {
        const int idx = base + j;
        int c = 0;
        if (idx < n) {
            for (int g = 0; g < EGRP; ++g) c += priv[(size_t)g * n_nodes + idx];
        }
        v[j] = local;
        local += c;
    }
    int incl = local;
#pragma unroll
    for (int d = 1; d < 64; d <<= 1) {
        int x = __shfl_up(incl, d);
        if (lane >= d) incl += x;
    }
    if (lane == 63) wsum[wid] = incl;
    __syncthreads();
    if (wid == 0) {
        int s = (lane < 16) ? wsum[lane] : 0;
#pragma unroll
        for (int d = 1; d < 16; d <<= 1) {
            int x = __shfl_up(s, d);
            if (lane >= d) s += x;
        }
        if (lane < 16) wsum[lane] = s;
    }
    __syncthreads();
    const int texcl = (incl - local) + (wid ? wsum[wid - 1] : 0);
#pragma unroll
    for (int j = 0; j < SCAN_ITEMS; ++j) {
        const int idx = base + j;
        if (idx < n) pre[idx] = texcl + v[j];
    }
    if (t == SCAN_BLOCK - 1) partials[blockIdx.x] = texcl + local;
}

// Pass 2: add block offset; final offsets + per-grp sub-offsets IN-PLACE over
// priv (read count, then overwrite with running offset — same thread).
__global__ __launch_bounds__(1024) void k_scan2(
    int* __restrict__ pre, const int* __restrict__ partials,
    int* __restrict__ po /* priv in, off2 out (in-place) */,
    int n, int n_nodes, int n_edges)
{
    __shared__ int s_off;
    const int t = threadIdx.x;
    if (t < 64) {
        int val = (t < blockIdx.x) ? partials[t] : 0;
#pragma unroll
        for (int d = 32; d > 0; d >>= 1) val += __shfl_down(val, d);
        if (t == 0) s_off = val;
    }
    __syncthreads();
    const int boff = s_off;
    const int base = blockIdx.x * (SCAN_BLOCK * SCAN_ITEMS) + t * SCAN_ITEMS;
#pragma unroll
    for (int j = 0; j < SCAN_ITEMS; ++j) {
        const int idx = base + j;
        if (idx < n) {
            const int o = boff + pre[idx];
            pre[idx] = o;
            int running = o;
            for (int g = 0; g < EGRP; ++g) {
                const size_t ix = (size_t)g * n_nodes + idx;
                const int c = po[ix];
                po[ix] = running;
                running += c;
            }
        }
    }
    if (blockIdx.x == 0 && t == 0) pre[n] = n_edges;
}

// ---------------------------------------------------------------------------
// k_place3: LDS cursors seeded from off2; reads partition-local staged data
// (dense), writes meta2 grouped by node. Zero global atomics.
// ---------------------------------------------------------------------------
__global__ __launch_bounds__(1024) void k_place3(
    const u32* __restrict__ ssrc, const u64* __restrict__ smrec,
    const int* __restrict__ pbase, const int* __restrict__ off2,
    u64* __restrict__ meta2, int n_nodes, int slice)
{
    __shared__ int cur[SLICE_MAX];
    const int p = blockIdx.x & (NPART - 1);
    const int g = blockIdx.x >> 3;
    const int t = threadIdx.x;

    const int lo = p * slice;
    const int hi = min(lo + slice, n_nodes);
    const int sl = hi - lo;
    if (sl <= 0) return;

    const int* __restrict__ o2 = off2 + (size_t)g * n_nodes + lo;
    for (int i = t; i < sl; i += 1024) cur[i] = o2[i];
    __syncthreads();

    const int pb = pbase[p], pe = pbase[p + 1];
    const long long len = pe - pb;
    const int beg = pb + (int)(len * g / EGRP);
    const int end = pb + (int)(len * (g + 1) / EGRP);
    for (int e = beg + t; e < end; e += 1024) {
        const int s = (int)ssrc[e];
        const int pos = atomicAdd(&cur[s - lo], 1);
        meta2[pos] = smrec[e];
    }
}

// ---------------------------------------------------------------------------
// Gather: partitioned; nt loads for one-touch streams (meta2, initp).
// ---------------------------------------------------------------------------
#define APPLY2(m, p, aR, aI)                                  \
    do {                                                      \
        const u32 nnv = (u32)((m) >> 32);                     \
        const float cr = unpack_lo(nnv);                      \
        const float ci = unpack_hi(nnv);                      \
        const float xr = unpack_lo(p);                        \
        const float xi = unpack_hi(p);                        \
        aR = fmaf(cr, xr, fmaf(-ci, xi, aR));                 \
        aI = fmaf(cr, xi, fmaf(ci, xr, aI));                  \
    } while (0)

__global__ __launch_bounds__(256) void k_gather(
    const u32* __restrict__ x1p, const u32* __restrict__ initp,
    const int* __restrict__ offsets, const u64* __restrict__ meta2,
    float* __restrict__ out_real, float* __restrict__ out_imag,
    int n_nodes, int slice)
{
    const int part = blockIdx.x & (NPART - 1);
    const int lane = threadIdx.x & 63;
    const int wip = ((blockIdx.x >> 3) << 2) + (threadIdx.x >> 6);
    const int wpp = (gridDim.x >> 3) << 2;

    const int lo = part * slice;
    const int hi = min(lo + slice, n_nodes);
    if (hi <= lo) return;
    const int chunk = (hi - lo + wpp - 1) / wpp;
    const int nbeg = lo + wip * chunk;
    const int nend = min(nbeg + chunk, hi);

    for (int n = nbeg; n < nend; ++n) {
        const int nu = __builtin_amdgcn_readfirstlane(n);
        const int beg = __builtin_amdgcn_readfirstlane(offsets[nu]);
        const int end = __builtin_amdgcn_readfirstlane(offsets[nu + 1]);

        float aR0 = 0.f, aI0 = 0.f, aR1 = 0.f, aI1 = 0.f;
        float aR2 = 0.f, aI2 = 0.f, aR3 = 0.f, aI3 = 0.f;

        int e = beg;
        for (; e + 8 <= end; e += 8) {
            const u64 m0 = __builtin_nontemporal_load(meta2 + e + 0);
            const u64 m1 = __builtin_nontemporal_load(meta2 + e + 1);
            const u64 m2 = __builtin_nontemporal_load(meta2 + e + 2);
            const u64 m3 = __builtin_nontemporal_load(meta2 + e + 3);
            const u64 m4 = __builtin_nontemporal_load(meta2 + e + 4);
            const u64 m5 = __builtin_nontemporal_load(meta2 + e + 5);
            const u64 m6 = __builtin_nontemporal_load(meta2 + e + 6);
            const u64 m7 = __builtin_nontemporal_load(meta2 + e + 7);
            const u32 p0 = x1p[(size_t)(u32)m0 * F + lane];
            const u32 p1 = x1p[(size_t)(u32)m1 * F + lane];
            const u32 p2 = x1p[(size_t)(u32)m2 * F + lane];
            const u32 p3 = x1p[(size_t)(u32)m3 * F + lane];
            const u32 p4 = x1p[(size_t)(u32)m4 * F + lane];
            const u32 p5 = x1p[(size_t)(u32)m5 * F + lane];
            const u32 p6 = x1p[(size_t)(u32)m6 * F + lane];
            const u32 p7 = x1p[(size_t)(u32)m7 * F + lane];
            APPLY2(m0, p0, aR0, aI0);
            APPLY2(m1, p1, aR1, aI1);
            APPLY2(m2, p2, aR2, aI2);
            APPLY2(m3, p3, aR3, aI3);
            APPLY2(m4, p4, aR0, aI0);
            APPLY2(m5, p5, aR1, aI1);
            APPLY2(m6, p6, aR2, aI2);
            APPLY2(m7, p7, aR3, aI3);
        }
        for (; e + 4 <= end; e += 4) {
            const u64 m0 = __builtin_nontemporal_load(meta2 + e + 0);
            const u64 m1 = __builtin_nontemporal_load(meta2 + e + 1);
            const u64 m2 = __builtin_nontemporal_load(meta2 + e + 2);
            const u64 m3 = __builtin_nontemporal_load(meta2 + e + 3);
            const u32 p0 = x1p[(size_t)(u32)m0 * F + lane];
            const u32 p1 = x1p[(size_t)(u32)m1 * F + lane];
            const u32 p2 = x1p[(size_t)(u32)m2 * F + lane];
            const u32 p3 = x1p[(size_t)(u32)m3 * F + lane];
            APPLY2(m0, p0, aR0, aI0);
            APPLY2(m1, p1, aR1, aI1);
            APPLY2(m2, p2, aR2, aI2);
            APPLY2(m3, p3, aR3, aI3);
        }
        for (; e < end; ++e) {
            const u64 m = __builtin_nontemporal_load(meta2 + e);
            const u32 p = x1p[(size_t)(u32)m * F + lane];
            APPLY2(m, p, aR0, aI0);
        }

        const size_t b = (size_t)nu * F + lane;
        const u32 iw = __builtin_nontemporal_load(initp + b); // aliases out_real[b]
        const float oR = unpack_lo(iw) + ((aR0 + aR1) + (aR2 + aR3));
        const float oI = unpack_hi(iw) + ((aI0 + aI1) + (aI2 + aI3));
        __builtin_nontemporal_store(oR, &out_real[b]);
        __builtin_nontemporal_store(oI, &out_imag[b]);
    }
}

// ---------------------------------------------------------------------------
// Fallback (ws too small or slice too big): f32 init + atomic scatter.
// ---------------------------------------------------------------------------
__global__ __launch_bounds__(256) void k_init_out(
    const float* __restrict__ x_real, const float* __restrict__ x_imag,
    const float* __restrict__ weight, const float* __restrict__ bias,
    float* __restrict__ out_real, float* __restrict__ out_imag, int n_nodes)
{
    const int lane = threadIdx.x & 63;
    const int waveId = (blockIdx.x * blockDim.x + threadIdx.x) >> 6;
    const int nWaves = (gridDim.x * blockDim.x) >> 6;
    const float* __restrict__ W0 = weight;
    float w0c[F];
#pragma unroll
    for (int k = 0; k < F; ++k) w0c[k] = W0[k * F + lane];
    const float bf = bias[lane];
    for (int n = waveId; n < n_nodes; n += nWaves) {
        const int nu = __builtin_amdgcn_readfirstlane(n);
        const float4* __restrict__ xr4 = (const float4*)(x_real + (size_t)nu * F);
        const float4* __restrict__ xi4 = (const float4*)(x_imag + (size_t)nu * F);
        float gR = 0.f, gI = 0.f;
#pragma unroll
        for (int k4 = 0; k4 < F / 4; ++k4) {
            const float4 vr = xr4[k4];
            const float4 vi = xi4[k4];
            const float xr[4] = {vr.x, vr.y, vr.z, vr.w};
            const float xi[4] = {vi.x, vi.y, vi.z, vi.w};
#pragma unroll
            for (int j = 0; j < 4; ++j) {
                const int k = 4 * k4 + j;
                gR = fmaf(xr[j], w0c[k], gR);
                gI = fmaf(xi[j], w0c[k], gI);
            }
        }
        const size_t b = (size_t)nu * F + lane;
        out_real[b] = gR + bf;
        out_imag[b] = gI + bf;
    }
}

__global__ __launch_bounds__(256) void k_x1_only(
    const float* __restrict__ x_real, const float* __restrict__ x_imag,
    const float* __restrict__ weight, u32* __restrict__ x1p, int n_nodes)
{
    const int lane = threadIdx.x & 63;
    const int waveId = (blockIdx.x * blockDim.x + threadIdx.x) >> 6;
    const int nWaves = (gridDim.x * blockDim.x) >> 6;
    const float* __restrict__ W1 = weight + F * F;
    float w1c[F];
#pragma unroll
    for (int k = 0; k < F; ++k) w1c[k] = W1[k * F + lane];
    for (int n = waveId; n < n_nodes; n += nWaves) {
        const int nu = __builtin_amdgcn_readfirstlane(n);
        const float4* __restrict__ xr4 = (const float4*)(x_real + (size_t)nu * F);
        const float4* __restrict__ xi4 = (const float4*)(x_imag + (size_t)nu * F);
        float aR = 0.f, aI = 0.f;
#pragma unroll
        for (int k4 = 0; k4 < F / 4; ++k4) {
            const float4 vr = xr4[k4];
            const float4 vi = xi4[k4];
            const float xr[4] = {vr.x, vr.y, vr.z, vr.w};
            const float xi[4] = {vi.x, vi.y, vi.z, vi.w};
#pragma unroll
            for (int j = 0; j < 4; ++j) {
                const int k = 4 * k4 + j;
                aR = fmaf(xr[j], w1c[k], aR);
                aI = fmaf(xi[j], w1c[k], aI);
            }
        }
        x1p[(size_t)nu * F + lane] = pack_bf16x2(aR, aI);
    }
}

__global__ __launch_bounds__(256) void k_scatter(
    const u32* __restrict__ x1p, const int* __restrict__ edge_index,
    const float* __restrict__ norm_real, const float* __restrict__ norm_imag,
    float* __restrict__ out_real, float* __restrict__ out_imag, int n_edges)
{
    const long long gid = (long long)blockIdx.x * blockDim.x + threadIdx.x;
    const long long total = (long long)n_edges * 16;
    if (gid >= total) return;
    const int e = (int)(gid >> 4);
    const int c = (int)(gid & 15);
    const int s = edge_index[e];
    const int d = edge_index[n_edges + e];
    const float cr = norm_real[e];
    const float ci = norm_imag[e];
    const uint4 p4 = *(const uint4*)(x1p + (size_t)d * F + c * 4);
    const u32 pp[4] = {p4.x, p4.y, p4.z, p4.w};
    float* __restrict__ pr = out_real + (size_t)s * F + c * 4;
    float* __restrict__ pi = out_imag + (size_t)s * F + c * 4;
#pragma unroll
    for (int j = 0; j < 4; ++j) {
        const float xr = unpack_lo(pp[j]);
        const float xi = unpack_hi(pp[j]);
        unsafeAtomicAdd(pr + j, fmaf(cr, xr, -ci * xi));
        unsafeAtomicAdd(pi + j, fmaf(cr, xi, ci * xr));
    }
}

extern "C" void kernel_launch(void* const* d_in, const int* in_sizes, int n_in,
                              void* d_out, int out_size, void* d_ws, size_t ws_size,
                              hipStream_t stream) {
    const float* x_real     = (const float*)d_in[0];
    const float* x_imag     = (const float*)d_in[1];
    const float* weight     = (const float*)d_in[2];
    const float* bias       = (const float*)d_in[3];
    const float* norm_real  = (const float*)d_in[4];
    const float* norm_imag  = (const float*)d_in[5];
    const int*   edge_index = (const int*)d_in[6];

    const int n_nodes = in_sizes[0] / F;
    const int n_edges = in_sizes[4];
    const int slice   = (n_nodes + NPART - 1) / NPART;

    float* out_real = (float*)d_out;
    float* out_imag = out_real + (size_t)n_nodes * F;
    u32*   initp    = (u32*)d_out;   // packed bf16 init, overwritten by gather

    // ws layout:
    //   region A (25.6 MB): staged_src(E*4)+staged_mrec(E*8) during CSR build,
    //                       then x1p (n*F*4) for gemm/gather (sequential reuse)
    //   [meta2][offsets][priv(=off2 in-place)][partials][pcnt|pbase|pcur]
    char* ws = (char*)d_ws;
    const size_t x1_bytes     = (size_t)n_nodes * F * sizeof(u32);     // 25.6 MB
    const size_t staged_bytes = (size_t)n_edges * 12;                  // 19.2 MB
    const size_t A_bytes      = (x1_bytes > staged_bytes ? x1_bytes : staged_bytes + 8);
    const size_t meta_bytes   = (size_t)n_edges * sizeof(u64);         // 12.8 MB
    const size_t off_bytes    = (size_t)(n_nodes + 1) * sizeof(int);
    const size_t priv_bytes   = (size_t)EGRP * n_nodes * sizeof(int);  // 12.8 MB
    const size_t par_bytes    = 64 * sizeof(int);
    const size_t small_bytes  = 32 * sizeof(int);   // pcnt[8], pbase[9], pcur[8]
    const size_t need = A_bytes + meta_bytes + off_bytes + priv_bytes + par_bytes + small_bytes;

    u32* x1p      = (u32*)ws;
    u32* ssrc     = (u32*)ws;
    u64* smrec    = (u64*)(ws + (size_t)n_edges * sizeof(u32));
    u64* meta2    = (u64*)(ws + A_bytes);
    int* offsets  = (int*)(ws + A_bytes + meta_bytes);
    int* priv     = (int*)(ws + A_bytes + meta_bytes + off_bytes);
    int* partials = (int*)(ws + A_bytes + meta_bytes + off_bytes + priv_bytes);
    int* pcnt     = partials + 64;
    int* pbase    = pcnt + NPART;
    int* pcur     = pbase + NPART + 1;

    if (ws_size >= need && slice <= SLICE_MAX) {
        (void)hipMemsetAsync(pcnt, 0, NPART * sizeof(int), stream);
        // --- CSR build (single-pass split) ---
        k_coarse<<<1024, 256, 0, stream>>>(edge_index, pcnt, n_edges, slice);
        k_base<<<1, 64, 0, stream>>>(pcnt, pbase, pcur);
        const int schunk = (n_edges + 511) / 512;
        k_split<<<512, 256, 0, stream>>>(edge_index, norm_real, norm_imag,
                                         pcur, ssrc, smrec, n_edges, slice, schunk);
        k_hist8<<<NPART * EGRP, 1024, 0, stream>>>(ssrc, pbase, priv, n_nodes, slice);
        const int sblocks = (n_nodes + SCAN_BLOCK * SCAN_ITEMS - 1) / (SCAN_BLOCK * SCAN_ITEMS);
        k_scan1<<<sblocks, SCAN_BLOCK, 0, stream>>>(priv, offsets, partials, n_nodes, n_nodes);
        k_scan2<<<sblocks, SCAN_BLOCK, 0, stream>>>(offsets, partials, priv,
                                                    n_nodes, n_nodes, n_edges);
        k_place3<<<NPART * EGRP, 1024, 0, stream>>>(ssrc, smrec, pbase, priv,
                                                    meta2, n_nodes, slice);
        // --- dense init (x1p overwrites staging) + gather ---
        const int gblocks = (n_nodes + 63) / 64;
        k_gemm<<<gblocks, 256, 0, stream>>>(
            x_real, x_imag, weight, bias, x1p, initp, n_nodes);
        k_gather<<<2048, 256, 0, stream>>>(
            x1p, initp, offsets, meta2, out_real, out_imag, n_nodes, slice);
    } else {
        k_init_out<<<2048, 256, 0, stream>>>(
            x_real, x_imag, weight, bias, out_real, out_imag, n_nodes);
        k_x1_only<<<2048, 256, 0, stream>>>(x_real, x_imag, weight, x1p, n_nodes);
        const long long work = (long long)n_edges * 16;
        const int blocks = (int)((work + 255) / 256);
        k_scatter<<<blocks, 256, 0, stream>>>(
            x1p, edge_index, norm_real, norm_imag, out_real, out_imag, n_edges);
    }
}

// Round 15
// 249.494 us; speedup vs baseline: 1.3060x; 1.3060x over previous
//
#include <hip/hip_runtime.h>

#define F 64
typedef unsigned int u32;
typedef unsigned long long u64;
typedef float f8 __attribute__((ext_vector_type(8)));

#define SCAN_BLOCK 1024
#define SCAN_ITEMS 4   // elements per thread -> 4096 per block
#define NPART 8        // node partitions
#define EGRP 32        // edge groups per partition (grid = 256)
#define SLICE_MAX 12544
#define SPLITB 512     // split blocks (chunks)
#define SITEMS 4       // edges per thread per split round

// ---- bf16x2 pack/unpack (RNE) ----------------------------------------------
__device__ __forceinline__ u32 pack_bf16x2(float lo, float hi) {
    u32 a = __float_as_uint(lo);
    u32 b = __float_as_uint(hi);
    a = (a + 0x7fffu + ((a >> 16) & 1u)) >> 16;
    b = (b + 0x7fffu + ((b >> 16) & 1u)) >> 16;
    return a | (b << 16);
}
__device__ __forceinline__ float unpack_lo(u32 p) { return __uint_as_float(p << 16); }
__device__ __forceinline__ float unpack_hi(u32 p) { return __uint_as_float(p & 0xffff0000u); }

// ---------------------------------------------------------------------------
// k_gemm: LDS-tiled GEMMs (unchanged).
// ---------------------------------------------------------------------------
__global__ __launch_bounds__(256, 4) void k_gemm(
    const float* __restrict__ x_real, const float* __restrict__ x_imag,
    const float* __restrict__ weight, const float* __restrict__ bias,
    u32* __restrict__ x1p, u32* __restrict__ initp, int n_nodes)
{
    __shared__ float xs[2][64 * 65];

    const int t = threadIdx.x;
    const int base_node = blockIdx.x * 64;

#pragma unroll
    for (int c = 0; c < 8; ++c) {
        const int fq  = t + 256 * c;
        const int arr = fq >> 10;
        const int rem = fq & 1023;
        const int n   = rem >> 4;
        const int c4  = rem & 15;
        const int g   = base_node + n;
        const float* __restrict__ s = arr ? x_imag : x_real;
        float4 v = make_float4(0.f, 0.f, 0.f, 0.f);
        if (g < n_nodes) v = *(const float4*)(s + (size_t)g * F + c4 * 4);
        float* d = &xs[arr][n * 65 + c4 * 4];
        d[0] = v.x; d[1] = v.y; d[2] = v.z; d[3] = v.w;
    }
    __syncthreads();

    const int lane = t & 63;
    const int f0 = __builtin_amdgcn_readfirstlane((t >> 6) * 16);
    const int g = base_node + lane;

    const float* __restrict__ W0 = weight;
    const float* __restrict__ W1 = weight + F * F;

    float aR0[16], aI0[16], aR1[16], aI1[16];
#pragma unroll
    for (int j = 0; j < 16; ++j) { aR0[j] = 0.f; aI0[j] = 0.f; aR1[j] = 0.f; aI1[j] = 0.f; }

    const float* __restrict__ xrow_r = &xs[0][lane * 65];
    const float* __restrict__ xrow_i = &xs[1][lane * 65];

    for (int k0 = 0; k0 < F; k0 += 4) {
#pragma unroll
        for (int kk = 0; kk < 4; ++kk) {
            const int k = k0 + kk;
            const float xr = xrow_r[k];
            const float xi = xrow_i[k];
            const f8 wa0 = *(const f8*)(W0 + k * F + f0);
            const f8 wb0 = *(const f8*)(W0 + k * F + f0 + 8);
            const f8 wa1 = *(const f8*)(W1 + k * F + f0);
            const f8 wb1 = *(const f8*)(W1 + k * F + f0 + 8);
#pragma unroll
            for (int j = 0; j < 8; ++j) {
                aR0[j]     = fmaf(xr, wa0[j], aR0[j]);
                aI0[j]     = fmaf(xi, wa0[j], aI0[j]);
                aR1[j]     = fmaf(xr, wa1[j], aR1[j]);
                aI1[j]     = fmaf(xi, wa1[j], aI1[j]);
                aR0[8 + j] = fmaf(xr, wb0[j], aR0[8 + j]);
                aI0[8 + j] = fmaf(xi, wb0[j], aI0[8 + j]);
                aR1[8 + j] = fmaf(xr, wb1[j], aR1[8 + j]);
                aI1[8 + j] = fmaf(xi, wb1[j], aI1[8 + j]);
            }
        }
    }

    if (g < n_nodes) {
        const f8 b0 = *(const f8*)(bias + f0);
        const f8 b1 = *(const f8*)(bias + f0 + 8);
        u32 pi[16], pw[16];
#pragma unroll
        for (int j = 0; j < 8; ++j) {
            pi[j]     = pack_bf16x2(aR0[j] + b0[j],     aI0[j] + b0[j]);
            pi[8 + j] = pack_bf16x2(aR0[8 + j] + b1[j], aI0[8 + j] + b1[j]);
            pw[j]     = pack_bf16x2(aR1[j],     aI1[j]);
            pw[8 + j] = pack_bf16x2(aR1[8 + j], aI1[8 + j]);
        }
        uint4* __restrict__ di = (uint4*)(initp + (size_t)g * F + f0);
        uint4* __restrict__ dw = (uint4*)(x1p  + (size_t)g * F + f0);
#pragma unroll
        for (int q = 0; q < 4; ++q) {
            di[q] = make_uint4(pi[4 * q], pi[4 * q + 1], pi[4 * q + 2], pi[4 * q + 3]);
            dw[q] = make_uint4(pw[4 * q], pw[4 * q + 1], pw[4 * q + 2], pw[4 * q + 3]);
        }
    }
}

// ---------------------------------------------------------------------------
// k_coarse: per-(block, partition) counts, plain stores. Same chunking as
// k_split. ZERO global atomics.
// ---------------------------------------------------------------------------
__global__ __launch_bounds__(256) void k_coarse(
    const int* __restrict__ src, int* __restrict__ bcnt,
    int n_edges, int slice, int chunk)
{
    __shared__ int c[NPART];
    const int t = threadIdx.x;
    if (t < NPART) c[t] = 0;
    __syncthreads();
    const int cbeg = blockIdx.x * chunk;
    const int cend = min(cbeg + chunk, n_edges);
    for (int e = cbeg + t; e < cend; e += 256)
        atomicAdd(&c[(u32)src[e] / (u32)slice], 1);
    __syncthreads();
    if (t < NPART) bcnt[blockIdx.x * NPART + t] = c[t];
}

// ---------------------------------------------------------------------------
// k_base2: one block. Partition-major scan of bcnt[512][8] -> exact
// bbase[block][part] start offsets + pbase[9]. Deterministic reservation.
// ---------------------------------------------------------------------------
__global__ __launch_bounds__(SPLITB) void k_base2(
    const int* __restrict__ bcnt, int* __restrict__ bbase, int* __restrict__ pbase)
{
    __shared__ int wsum[SPLITB / 64];
    __shared__ int total[NPART];
    __shared__ int pb[NPART + 1];
    const int t = threadIdx.x;          // 0..511
    const int lane = t & 63, wid = t >> 6;

    for (int p = 0; p < NPART; ++p) {
        const int v = bcnt[t * NPART + p];
        int incl = v;
#pragma unroll
        for (int d = 1; d < 64; d <<= 1) {
            int x = __shfl_up(incl, d);
            if (lane >= d) incl += x;
        }
        if (lane == 63) wsum[wid] = incl;
        __syncthreads();
        if (wid == 0) {
            int s = (lane < SPLITB / 64) ? wsum[lane] : 0;
#pragma unroll
            for (int d = 1; d < SPLITB / 64; d <<= 1) {
                int x = __shfl_up(s, d);
                if (lane >= d) s += x;
            }
            if (lane < SPLITB / 64) wsum[lane] = s;
        }
        __syncthreads();
        const int excl = (incl - v) + (wid ? wsum[wid - 1] : 0);
        bbase[t * NPART + p] = excl;
        if (t == SPLITB - 1) total[p] = excl + v;
        __syncthreads();
    }
    if (t == 0) {
        int run = 0;
        for (int p = 0; p < NPART; ++p) { pb[p] = run; run += total[p]; }
        pb[NPART] = run;
        for (int p = 0; p <= NPART; ++p) pbase[p] = pb[p];
    }
    __syncthreads();
    for (int p = 0; p < NPART; ++p)
        bbase[t * NPART + p] += pb[p];
}

// ---------------------------------------------------------------------------
// k_split: ONE pass, ZERO global atomics. LDS cursors seeded from bbase;
// 1024 edges per round (SITEMS=4). Block's writes per partition contiguous.
// ---------------------------------------------------------------------------
__global__ __launch_bounds__(256) void k_split(
    const int* __restrict__ ei, const float* __restrict__ nr, const float* __restrict__ ni,
    const int* __restrict__ bbase, u32* __restrict__ ssrc, u64* __restrict__ smrec,
    int n_edges, int slice, int chunk)
{
    __shared__ int cnt[NPART];
    __shared__ int gb[NPART];
    __shared__ int lcur[NPART];
    const int t = threadIdx.x;
    if (t < NPART) lcur[t] = bbase[blockIdx.x * NPART + t];
    const int cbeg = blockIdx.x * chunk;
    const int cend = min(cbeg + chunk, n_edges);

    for (int base = cbeg; base < cend; base += 256 * SITEMS) {
        if (t < NPART) cnt[t] = 0;
        __syncthreads();
        int p[SITEMS], lpos[SITEMS];
        u32 s[SITEMS]; u64 mrec[SITEMS];
#pragma unroll
        for (int j = 0; j < SITEMS; ++j) {
            const int e = base + t + 256 * j;
            if (e < cend) {
                s[j] = (u32)ei[e];
                const u32 d = (u32)ei[n_edges + e];
                const u32 nn = pack_bf16x2(nr[e], ni[e]);
                mrec[j] = (u64)d | ((u64)nn << 32);
                p[j] = (int)(s[j] / (u32)slice);
                lpos[j] = atomicAdd(&cnt[p[j]], 1);
            } else p[j] = -1;
        }
        __syncthreads();
        if (t < NPART) { gb[t] = lcur[t]; lcur[t] += cnt[t]; }
        __syncthreads();
#pragma unroll
        for (int j = 0; j < SITEMS; ++j) {
            if (p[j] >= 0) {
                const int gi = gb[p[j]] + lpos[j];
                ssrc[gi]  = s[j];
                smrec[gi] = mrec[j];
            }
        }
        __syncthreads();
    }
}

// ---------------------------------------------------------------------------
// k_hist8: per (part, grp): LDS histogram of staged src -> priv[grp][node].
// ---------------------------------------------------------------------------
__global__ __launch_bounds__(1024) void k_hist8(
    const u32* __restrict__ ssrc, const int* __restrict__ pbase,
    int* __restrict__ priv, int n_nodes, int slice)
{
    __shared__ int h[SLICE_MAX];
    const int p = blockIdx.x & (NPART - 1);
    const int g = blockIdx.x >> 3;
    const int t = threadIdx.x;

    const int lo = p * slice;
    const int hi = min(lo + slice, n_nodes);
    const int sl = hi - lo;
    if (sl <= 0) return;

    for (int i = t; i < sl; i += 1024) h[i] = 0;
    __syncthreads();

    const int pb = pbase[p], pe = pbase[p + 1];
    const long long len = pe - pb;
    const int beg = pb + (int)(len * g / EGRP);
    const int end = pb + (int)(len * (g + 1) / EGRP);
    for (int e = beg + t; e < end; e += 1024)
        atomicAdd(&h[(int)ssrc[e] - lo], 1);
    __syncthreads();

    int* __restrict__ dst = priv + (size_t)g * n_nodes + lo;
    for (int i = t; i < sl; i += 1024) dst[i] = h[i];
}

// ---------------------------------------------------------------------------
// Scan pass 1: per-node count = sum_g priv[g][node]; block-local prefix.
// ---------------------------------------------------------------------------
__global__ __launch_bounds__(1024) void k_scan1(
    const int* __restrict__ priv, int* __restrict__ pre,
    int* __restrict__ partials, int n, int n_nodes)
{
    __shared__ int wsum[16];
    const int t = threadIdx.x;
    const int lane = t & 63, wid = t >> 6;
    const int base = blockIdx.x * (SCAN_BLOCK * SCAN_ITEMS) + t * SCAN_ITEMS;

    int v[SCAN_ITEMS];
    int local = 0;
#pragma unroll
    for (int j = 0; j < SCAN_ITEMS; ++j) {
        const int idx = base + j;
        int c = 0;
        if (idx < n) {
            for (int g = 0; g < EGRP; ++g) c += priv[(size_t)g * n_nodes + idx];
        }
        v[j] = local;
        local += c;
    }
    int incl = local;
#pragma unroll
    for (int d = 1; d < 64; d <<= 1) {
        int x = __shfl_up(incl, d);
        if (lane >= d) incl += x;
    }
    if (lane == 63) wsum[wid] = incl;
    __syncthreads();
    if (wid == 0) {
        int s = (lane < 16) ? wsum[lane] : 0;
#pragma unroll
        for (int d = 1; d < 16; d <<= 1) {
            int x = __shfl_up(s, d);
            if (lane >= d) s += x;
        }
        if (lane < 16) wsum[lane] = s;
    }
    __syncthreads();
    const int texcl = (incl - local) + (wid ? wsum[wid - 1] : 0);
#pragma unroll
    for (int j = 0; j < SCAN_ITEMS; ++j) {
        const int idx = base + j;
        if (idx < n) pre[idx] = texcl + v[j];
    }
    if (t == SCAN_BLOCK - 1) partials[blockIdx.x] = texcl + local;
}

// Pass 2: add block offset; final offsets + per-grp sub-offsets IN-PLACE.
__global__ __launch_bounds__(1024) void k_scan2(
    int* __restrict__ pre, const int* __restrict__ partials,
    int* __restrict__ po, int n, int n_nodes, int n_edges)
{
    __shared__ int s_off;
    const int t = threadIdx.x;
    if (t < 64) {
        int val = (t < blockIdx.x) ? partials[t] : 0;
#pragma unroll
        for (int d = 32; d > 0; d >>= 1) val += __shfl_down(val, d);
        if (t == 0) s_off = val;
    }
    __syncthreads();
    const int boff = s_off;
    const int base = blockIdx.x * (SCAN_BLOCK * SCAN_ITEMS) + t * SCAN_ITEMS;
#pragma unroll
    for (int j = 0; j < SCAN_ITEMS; ++j) {
        const int idx = base + j;
        if (idx < n) {
            const int o = boff + pre[idx];
            pre[idx] = o;
            int running = o;
            for (int g = 0; g < EGRP; ++g) {
                const size_t ix = (size_t)g * n_nodes + idx;
                const int c = po[ix];
                po[ix] = running;
                running += c;
            }
        }
    }
    if (blockIdx.x == 0 && t == 0) pre[n] = n_edges;
}

// ---------------------------------------------------------------------------
// k_place3: LDS cursors seeded from off2; partition-local staged reads.
// ---------------------------------------------------------------------------
__global__ __launch_bounds__(1024) void k_place3(
    const u32* __restrict__ ssrc, const u64* __restrict__ smrec,
    const int* __restrict__ pbase, const int* __restrict__ off2,
    u64* __restrict__ meta2, int n_nodes, int slice)
{
    __shared__ int cur[SLICE_MAX];
    const int p = blockIdx.x & (NPART - 1);
    const int g = blockIdx.x >> 3;
    const int t = threadIdx.x;

    const int lo = p * slice;
    const int hi = min(lo + slice, n_nodes);
    const int sl = hi - lo;
    if (sl <= 0) return;

    const int* __restrict__ o2 = off2 + (size_t)g * n_nodes + lo;
    for (int i = t; i < sl; i += 1024) cur[i] = o2[i];
    __syncthreads();

    const int pb = pbase[p], pe = pbase[p + 1];
    const long long len = pe - pb;
    const int beg = pb + (int)(len * g / EGRP);
    const int end = pb + (int)(len * (g + 1) / EGRP);
    for (int e = beg + t; e < end; e += 1024) {
        const int s = (int)ssrc[e];
        const int pos = atomicAdd(&cur[s - lo], 1);
        meta2[pos] = smrec[e];
    }
}

// ---------------------------------------------------------------------------
// Gather: partitioned; nt loads for one-touch streams (meta2, initp).
// ---------------------------------------------------------------------------
#define APPLY2(m, p, aR, aI)                                  \
    do {                                                      \
        const u32 nnv = (u32)((m) >> 32);                     \
        const float cr = unpack_lo(nnv);                      \
        const float ci = unpack_hi(nnv);                      \
        const float xr = unpack_lo(p);                        \
        const float xi = unpack_hi(p);                        \
        aR = fmaf(cr, xr, fmaf(-ci, xi, aR));                 \
        aI = fmaf(cr, xi, fmaf(ci, xr, aI));                  \
    } while (0)

__global__ __launch_bounds__(256) void k_gather(
    const u32* __restrict__ x1p, const u32* __restrict__ initp,
    const int* __restrict__ offsets, const u64* __restrict__ meta2,
    float* __restrict__ out_real, float* __restrict__ out_imag,
    int n_nodes, int slice)
{
    const int part = blockIdx.x & (NPART - 1);
    const int lane = threadIdx.x & 63;
    const int wip = ((blockIdx.x >> 3) << 2) + (threadIdx.x >> 6);
    const int wpp = (gridDim.x >> 3) << 2;

    const int lo = part * slice;
    const int hi = min(lo + slice, n_nodes);
    if (hi <= lo) return;
    const int chunk = (hi - lo + wpp - 1) / wpp;
    const int nbeg = lo + wip * chunk;
    const int nend = min(nbeg + chunk, hi);

    for (int n = nbeg; n < nend; ++n) {
        const int nu = __builtin_amdgcn_readfirstlane(n);
        const int beg = __builtin_amdgcn_readfirstlane(offsets[nu]);
        const int end = __builtin_amdgcn_readfirstlane(offsets[nu + 1]);

        float aR0 = 0.f, aI0 = 0.f, aR1 = 0.f, aI1 = 0.f;
        float aR2 = 0.f, aI2 = 0.f, aR3 = 0.f, aI3 = 0.f;

        int e = beg;
        for (; e + 8 <= end; e += 8) {
            const u64 m0 = __builtin_nontemporal_load(meta2 + e + 0);
            const u64 m1 = __builtin_nontemporal_load(meta2 + e + 1);
            const u64 m2 = __builtin_nontemporal_load(meta2 + e + 2);
            const u64 m3 = __builtin_nontemporal_load(meta2 + e + 3);
            const u64 m4 = __builtin_nontemporal_load(meta2 + e + 4);
            const u64 m5 = __builtin_nontemporal_load(meta2 + e + 5);
            const u64 m6 = __builtin_nontemporal_load(meta2 + e + 6);
            const u64 m7 = __builtin_nontemporal_load(meta2 + e + 7);
            const u32 p0 = x1p[(size_t)(u32)m0 * F + lane];
            const u32 p1 = x1p[(size_t)(u32)m1 * F + lane];
            const u32 p2 = x1p[(size_t)(u32)m2 * F + lane];
            const u32 p3 = x1p[(size_t)(u32)m3 * F + lane];
            const u32 p4 = x1p[(size_t)(u32)m4 * F + lane];
            const u32 p5 = x1p[(size_t)(u32)m5 * F + lane];
            const u32 p6 = x1p[(size_t)(u32)m6 * F + lane];
            const u32 p7 = x1p[(size_t)(u32)m7 * F + lane];
            APPLY2(m0, p0, aR0, aI0);
            APPLY2(m1, p1, aR1, aI1);
            APPLY2(m2, p2, aR2, aI2);
            APPLY2(m3, p3, aR3, aI3);
            APPLY2(m4, p4, aR0, aI0);
            APPLY2(m5, p5, aR1, aI1);
            APPLY2(m6, p6, aR2, aI2);
            APPLY2(m7, p7, aR3, aI3);
        }
        for (; e + 4 <= end; e += 4) {
            const u64 m0 = __builtin_nontemporal_load(meta2 + e + 0);
            const u64 m1 = __builtin_nontemporal_load(meta2 + e + 1);
            const u64 m2 = __builtin_nontemporal_load(meta2 + e + 2);
            const u64 m3 = __builtin_nontemporal_load(meta2 + e + 3);
            const u32 p0 = x1p[(size_t)(u32)m0 * F + lane];
            const u32 p1 = x1p[(size_t)(u32)m1 * F + lane];
            const u32 p2 = x1p[(size_t)(u32)m2 * F + lane];
            const u32 p3 = x1p[(size_t)(u32)m3 * F + lane];
            APPLY2(m0, p0, aR0, aI0);
            APPLY2(m1, p1, aR1, aI1);
            APPLY2(m2, p2, aR2, aI2);
            APPLY2(m3, p3, aR3, aI3);
        }
        for (; e < end; ++e) {
            const u64 m = __builtin_nontemporal_load(meta2 + e);
            const u32 p = x1p[(size_t)(u32)m * F + lane];
            APPLY2(m, p, aR0, aI0);
        }

        const size_t b = (size_t)nu * F + lane;
        const u32 iw = __builtin_nontemporal_load(initp + b); // aliases out_real[b]
        const float oR = unpack_lo(iw) + ((aR0 + aR1) + (aR2 + aR3));
        const float oI = unpack_hi(iw) + ((aI0 + aI1) + (aI2 + aI3));
        __builtin_nontemporal_store(oR, &out_real[b]);
        __builtin_nontemporal_store(oI, &out_imag[b]);
    }
}

// ---------------------------------------------------------------------------
// Fallback (ws too small or slice too big): f32 init + atomic scatter.
// ---------------------------------------------------------------------------
__global__ __launch_bounds__(256) void k_init_out(
    const float* __restrict__ x_real, const float* __restrict__ x_imag,
    const float* __restrict__ weight, const float* __restrict__ bias,
    float* __restrict__ out_real, float* __restrict__ out_imag, int n_nodes)
{
    const int lane = threadIdx.x & 63;
    const int waveId = (blockIdx.x * blockDim.x + threadIdx.x) >> 6;
    const int nWaves = (gridDim.x * blockDim.x) >> 6;
    const float* __restrict__ W0 = weight;
    float w0c[F];
#pragma unroll
    for (int k = 0; k < F; ++k) w0c[k] = W0[k * F + lane];
    const float bf = bias[lane];
    for (int n = waveId; n < n_nodes; n += nWaves) {
        const int nu = __builtin_amdgcn_readfirstlane(n);
        const float4* __restrict__ xr4 = (const float4*)(x_real + (size_t)nu * F);
        const float4* __restrict__ xi4 = (const float4*)(x_imag + (size_t)nu * F);
        float gR = 0.f, gI = 0.f;
#pragma unroll
        for (int k4 = 0; k4 < F / 4; ++k4) {
            const float4 vr = xr4[k4];
            const float4 vi = xi4[k4];
            const float xr[4] = {vr.x, vr.y, vr.z, vr.w};
            const float xi[4] = {vi.x, vi.y, vi.z, vi.w};
#pragma unroll
            for (int j = 0; j < 4; ++j) {
                const int k = 4 * k4 + j;
                gR = fmaf(xr[j], w0c[k], gR);
                gI = fmaf(xi[j], w0c[k], gI);
            }
        }
        const size_t b = (size_t)nu * F + lane;
        out_real[b] = gR + bf;
        out_imag[b] = gI + bf;
    }
}

__global__ __launch_bounds__(256) void k_x1_only(
    const float* __restrict__ x_real, const float* __restrict__ x_imag,
    const float* __restrict__ weight, u32* __restrict__ x1p, int n_nodes)
{
    const int lane = threadIdx.x & 63;
    const int waveId = (blockIdx.x * blockDim.x + threadIdx.x) >> 6;
    const int nWaves = (gridDim.x * blockDim.x) >> 6;
    const float* __restrict__ W1 = weight + F * F;
    float w1c[F];
#pragma unroll
    for (int k = 0; k < F; ++k) w1c[k] = W1[k * F + lane];
    for (int n = waveId; n < n_nodes; n += nWaves) {
        const int nu = __builtin_amdgcn_readfirstlane(n);
        const float4* __restrict__ xr4 = (const float4*)(x_real + (size_t)nu * F);
        const float4* __restrict__ xi4 = (const float4*)(x_imag + (size_t)nu * F);
        float aR = 0.f, aI = 0.f;
#pragma unroll
        for (int k4 = 0; k4 < F / 4; ++k4) {
            const float4 vr = xr4[k4];
            const float4 vi = xi4[k4];
            const float xr[4] = {vr.x, vr.y, vr.z, vr.w};
            const float xi[4] = {vi.x, vi.y, vi.z, vi.w};
#pragma unroll
            for (int j = 0; j < 4; ++j) {
                const int k = 4 * k4 + j;
                aR = fmaf(xr[j], w1c[k], aR);
                aI = fmaf(xi[j], w1c[k], aI);
            }
        }
        x1p[(size_t)nu * F + lane] = pack_bf16x2(aR, aI);
    }
}

__global__ __launch_bounds__(256) void k_scatter(
    const u32* __restrict__ x1p, const int* __restrict__ edge_index,
    const float* __restrict__ norm_real, const float* __restrict__ norm_imag,
    float* __restrict__ out_real, float* __restrict__ out_imag, int n_edges)
{
    const long long gid = (long long)blockIdx.x * blockDim.x + threadIdx.x;
    const long long total = (long long)n_edges * 16;
    if (gid >= total) return;
    const int e = (int)(gid >> 4);
    const int c = (int)(gid & 15);
    const int s = edge_index[e];
    const int d = edge_index[n_edges + e];
    const float cr = norm_real[e];
    const float ci = norm_imag[e];
    const uint4 p4 = *(const uint4*)(x1p + (size_t)d * F + c * 4);
    const u32 pp[4] = {p4.x, p4.y, p4.z, p4.w};
    float* __restrict__ pr = out_real + (size_t)s * F + c * 4;
    float* __restrict__ pi = out_imag + (size_t)s * F + c * 4;
#pragma unroll
    for (int j = 0; j < 4; ++j) {
        const float xr = unpack_lo(pp[j]);
        const float xi = unpack_hi(pp[j]);
        unsafeAtomicAdd(pr + j, fmaf(cr, xr, -ci * xi));
        unsafeAtomicAdd(pi + j, fmaf(cr, xi, ci * xr));
    }
}

extern "C" void kernel_launch(void* const* d_in, const int* in_sizes, int n_in,
                              void* d_out, int out_size, void* d_ws, size_t ws_size,
                              hipStream_t stream) {
    const float* x_real     = (const float*)d_in[0];
    const float* x_imag     = (const float*)d_in[1];
    const float* weight     = (const float*)d_in[2];
    const float* bias       = (const float*)d_in[3];
    const float* norm_real  = (const float*)d_in[4];
    const float* norm_imag  = (const float*)d_in[5];
    const int*   edge_index = (const int*)d_in[6];

    const int n_nodes = in_sizes[0] / F;
    const int n_edges = in_sizes[4];
    const int slice   = (n_nodes + NPART - 1) / NPART;

    float* out_real = (float*)d_out;
    float* out_imag = out_real + (size_t)n_nodes * F;
    u32*   initp    = (u32*)d_out;   // packed bf16 init, overwritten by gather

    // ws layout:
    //   region A: staged ssrc(E*4)+smrec(E*8) during CSR build, then x1p
    //   [meta2][offsets][priv(=off2)][partials][bcnt][bbase][pbase]
    char* ws = (char*)d_ws;
    const size_t x1_bytes     = (size_t)n_nodes * F * sizeof(u32);
    const size_t staged_bytes = (size_t)n_edges * 12;
    const size_t A_bytes      = (x1_bytes > staged_bytes ? x1_bytes : staged_bytes + 8);
    const size_t meta_bytes   = (size_t)n_edges * sizeof(u64);
    const size_t off_bytes    = (size_t)(n_nodes + 1) * sizeof(int);
    const size_t priv_bytes   = (size_t)EGRP * n_nodes * sizeof(int);
    const size_t par_bytes    = 64 * sizeof(int);
    const size_t bcnt_bytes   = (size_t)SPLITB * NPART * sizeof(int);
    const size_t bbase_bytes  = (size_t)SPLITB * NPART * sizeof(int);
    const size_t pbase_bytes  = (NPART + 1) * sizeof(int);
    const size_t need = A_bytes + meta_bytes + off_bytes + priv_bytes + par_bytes
                      + bcnt_bytes + bbase_bytes + pbase_bytes;

    u32* x1p      = (u32*)ws;
    u32* ssrc     = (u32*)ws;
    u64* smrec    = (u64*)(ws + (size_t)n_edges * sizeof(u32));
    u64* meta2    = (u64*)(ws + A_bytes);
    int* offsets  = (int*)(ws + A_bytes + meta_bytes);
    int* priv     = (int*)(ws + A_bytes + meta_bytes + off_bytes);
    int* partials = (int*)(ws + A_bytes + meta_bytes + off_bytes + priv_bytes);
    int* bcnt     = partials + 64;
    int* bbase    = bcnt + SPLITB * NPART;
    int* pbase    = bbase + SPLITB * NPART;

    if (ws_size >= need && slice <= SLICE_MAX) {
        const int schunk = (n_edges + SPLITB - 1) / SPLITB;
        // --- CSR build: deterministic single-pass split, zero global atomics ---
        k_coarse<<<SPLITB, 256, 0, stream>>>(edge_index, bcnt, n_edges, slice, schunk);
        k_base2<<<1, SPLITB, 0, stream>>>(bcnt, bbase, pbase);
        k_split<<<SPLITB, 256, 0, stream>>>(edge_index, norm_real, norm_imag,
                                            bbase, ssrc, smrec, n_edges, slice, schunk);
        k_hist8<<<NPART * EGRP, 1024, 0, stream>>>(ssrc, pbase, priv, n_nodes, slice);
        const int sblocks = (n_nodes + SCAN_BLOCK * SCAN_ITEMS - 1) / (SCAN_BLOCK * SCAN_ITEMS);
        k_scan1<<<sblocks, SCAN_BLOCK, 0, stream>>>(priv, offsets, partials, n_nodes, n_nodes);
        k_scan2<<<sblocks, SCAN_BLOCK, 0, stream>>>(offsets, partials, priv,
                                                    n_nodes, n_nodes, n_edges);
        k_place3<<<NPART * EGRP, 1024, 0, stream>>>(ssrc, smrec, pbase, priv,
                                                    meta2, n_nodes, slice);
        // --- dense init (x1p overwrites staging) + gather ---
        const int gblocks = (n_nodes + 63) / 64;
        k_gemm<<<gblocks, 256, 0, stream>>>(
            x_real, x_imag, weight, bias, x1p, initp, n_nodes);
        k_gather<<<2048, 256, 0, stream>>>(
            x1p, initp, offsets, meta2, out_real, out_imag, n_nodes, slice);
    } else {
        k_init_out<<<2048, 256, 0, stream>>>(
            x_real, x_imag, weight, bias, out_real, out_imag, n_nodes);
        k_x1_only<<<2048, 256, 0, stream>>>(x_real, x_imag, weight, x1p, n_nodes);
        const long long work = (long long)n_edges * 16;
        const int blocks = (int)((work + 255) / 256);
        k_scatter<<<blocks, 256, 0, stream>>>(
            x1p, edge_index, norm_real, norm_imag, out_real, out_imag, n_edges);
    }
}

// Round 16
// 226.064 us; speedup vs baseline: 1.4414x; 1.1036x over previous
//
#include <hip/hip_runtime.h>

#define F 64
typedef unsigned int u32;
typedef unsigned long long u64;
typedef short bf16x8 __attribute__((ext_vector_type(8)));
typedef float f32x4 __attribute__((ext_vector_type(4)));

#define SCAN_BLOCK 1024
#define SCAN_ITEMS 4   // elements per thread -> 4096 per block
#define NPART 8        // node partitions
#define EGRP 32        // edge groups per partition (grid = 256)
#define SLICE_MAX 12544
#define SPLITB 512     // split blocks (chunks)
#define SITEMS 4       // edges per thread per split round

// ---- bf16x2 pack/unpack (RNE) ----------------------------------------------
__device__ __forceinline__ u32 pack_bf16x2(float lo, float hi) {
    u32 a = __float_as_uint(lo);
    u32 b = __float_as_uint(hi);
    a = (a + 0x7fffu + ((a >> 16) & 1u)) >> 16;
    b = (b + 0x7fffu + ((b >> 16) & 1u)) >> 16;
    return a | (b << 16);
}
__device__ __forceinline__ float unpack_lo(u32 p) { return __uint_as_float(p << 16); }
__device__ __forceinline__ float unpack_hi(u32 p) { return __uint_as_float(p & 0xffff0000u); }

// ---------------------------------------------------------------------------
// k_gemm (MFMA): per 64-node block computes [128 rows (node-interleaved
// real/imag) x 64k] @ [64k x 128 f (W0|W1)] with mfma_f32_16x16x32_bf16.
//   initp[n][f] = pack_bf16(x_r@W0+b, x_i@W0+b)   (f < 64)
//   x1p[n][f]   = pack_bf16(x_r@W1,   x_i@W1)     (f >= 64)
// LDS: A[128][64] bf16 + Bt[128][64] bf16, kgroup XOR-swizzled (kg ^= row&7)
// so ds_read_b128 fragment loads are conflict-free and 16B-aligned.
// ---------------------------------------------------------------------------
__global__ __launch_bounds__(256, 4) void k_gemm(
    const float* __restrict__ x_real, const float* __restrict__ x_imag,
    const float* __restrict__ weight, const float* __restrict__ bias,
    u32* __restrict__ x1p, u32* __restrict__ initp, int n_nodes)
{
    __shared__ unsigned short lds[2 * 128 * 64];   // 32 KB
    unsigned short* __restrict__ A  = lds;
    unsigned short* __restrict__ Bt = lds + 128 * 64;

    const int t = threadIdx.x;
    const int base = blockIdx.x * 64;   // node base

    // ---- stage A: x rows, row = 2*ln + (0 real | 1 imag), bf16, swizzled ----
#pragma unroll
    for (int c = 0; c < 8; ++c) {
        const int fq  = t + 256 * c;          // 2048 float4 slots
        const int arr = fq >> 10;
        const int rem = fq & 1023;
        const int ln  = rem >> 4;
        const int c4  = rem & 15;
        const int g   = base + ln;
        const float* __restrict__ s = arr ? x_imag : x_real;
        float4 v = make_float4(0.f, 0.f, 0.f, 0.f);
        if (g < n_nodes) v = *(const float4*)(s + (size_t)g * F + c4 * 4);
        const int row  = 2 * ln + arr;
        const int kg   = c4 >> 1;
        const int half = c4 & 1;
        u32* dst = (u32*)&A[row * 64 + ((kg ^ (row & 7)) << 3) + (half << 2)];
        dst[0] = pack_bf16x2(v.x, v.y);
        dst[1] = pack_bf16x2(v.z, v.w);
    }

    // ---- stage Bt: Bt[f2][k] = W{0|1}[k][f2&63], bf16, swizzled ----
    {
        const int f2 = t & 127;
        const int khalf = t >> 7;
        const float* __restrict__ wsrc = weight + (f2 >= 64 ? F * F : 0) + (f2 & 63);
        const int swz = f2 & 7;
#pragma unroll 4
        for (int kk = 0; kk < 32; ++kk) {
            const int k = khalf * 32 + kk;
            const float wv = wsrc[(size_t)k * F];
            Bt[f2 * 64 + (((k >> 3) ^ swz) << 3) + (k & 7)] =
                (unsigned short)(pack_bf16x2(wv, 0.f) & 0xffffu);
        }
    }
    __syncthreads();

    // ---- MFMA compute: wave w -> rows [w*32, w*32+32), all 128 cols ----
    const int l   = t & 63;
    const int w   = t >> 6;
    const int l15 = l & 15;
    const int lg  = l >> 4;

    f32x4 acc[2][8];
#pragma unroll
    for (int tr = 0; tr < 2; ++tr)
#pragma unroll
        for (int tc = 0; tc < 8; ++tc)
            acc[tr][tc] = (f32x4){0.f, 0.f, 0.f, 0.f};

#pragma unroll
    for (int ks = 0; ks < 2; ++ks) {
        bf16x8 af[2];
#pragma unroll
        for (int tr = 0; tr < 2; ++tr) {
            const int row = w * 32 + tr * 16 + l15;
            const int kg  = ks * 4 + lg;
            af[tr] = *(const bf16x8*)&A[row * 64 + ((kg ^ (row & 7)) << 3)];
        }
#pragma unroll
        for (int tc = 0; tc < 8; ++tc) {
            const int f2 = tc * 16 + l15;
            const int kg = ks * 4 + lg;
            const bf16x8 bfr = *(const bf16x8*)&Bt[f2 * 64 + ((kg ^ (f2 & 7)) << 3)];
#pragma unroll
            for (int tr = 0; tr < 2; ++tr)
                acc[tr][tc] = __builtin_amdgcn_mfma_f32_16x16x32_bf16(
                    af[tr], bfr, acc[tr][tc], 0, 0, 0);
        }
    }

    // ---- epilogue: acc regs {0,1} = (real,imag) node g0; {2,3} = node g0+1 ----
#pragma unroll
    for (int tc = 0; tc < 8; ++tc) {
        const int f2 = tc * 16 + l15;
        const float bv = (f2 < F) ? bias[f2] : 0.f;
#pragma unroll
        for (int tr = 0; tr < 2; ++tr) {
            const int row0 = w * 32 + tr * 16 + lg * 4;
            const int g0 = base + (row0 >> 1);
            const int g1 = g0 + 1;
            const f32x4 a = acc[tr][tc];
            if (f2 < F) {
                if (g0 < n_nodes) initp[(size_t)g0 * F + f2] = pack_bf16x2(a[0] + bv, a[1] + bv);
                if (g1 < n_nodes) initp[(size_t)g1 * F + f2] = pack_bf16x2(a[2] + bv, a[3] + bv);
            } else {
                const int f = f2 - F;
                if (g0 < n_nodes) x1p[(size_t)g0 * F + f] = pack_bf16x2(a[0], a[1]);
                if (g1 < n_nodes) x1p[(size_t)g1 * F + f] = pack_bf16x2(a[2], a[3]);
            }
        }
    }
}

// ---------------------------------------------------------------------------
// k_coarse: per-(block, partition) counts, plain stores. ZERO global atomics.
// ---------------------------------------------------------------------------
__global__ __launch_bounds__(256) void k_coarse(
    const int* __restrict__ src, int* __restrict__ bcnt,
    int n_edges, int slice, int chunk)
{
    __shared__ int c[NPART];
    const int t = threadIdx.x;
    if (t < NPART) c[t] = 0;
    __syncthreads();
    const int cbeg = blockIdx.x * chunk;
    const int cend = min(cbeg + chunk, n_edges);
    for (int e = cbeg + t; e < cend; e += 256)
        atomicAdd(&c[(u32)src[e] / (u32)slice], 1);
    __syncthreads();
    if (t < NPART) bcnt[blockIdx.x * NPART + t] = c[t];
}

// ---------------------------------------------------------------------------
// k_base2: one block. Partition-major scan of bcnt -> bbase + pbase[9].
// ---------------------------------------------------------------------------
__global__ __launch_bounds__(SPLITB) void k_base2(
    const int* __restrict__ bcnt, int* __restrict__ bbase, int* __restrict__ pbase)
{
    __shared__ int wsum[SPLITB / 64];
    __shared__ int total[NPART];
    __shared__ int pb[NPART + 1];
    const int t = threadIdx.x;
    const int lane = t & 63, wid = t >> 6;

    for (int p = 0; p < NPART; ++p) {
        const int v = bcnt[t * NPART + p];
        int incl = v;
#pragma unroll
        for (int d = 1; d < 64; d <<= 1) {
            int x = __shfl_up(incl, d);
            if (lane >= d) incl += x;
        }
        if (lane == 63) wsum[wid] = incl;
        __syncthreads();
        if (wid == 0) {
            int s = (lane < SPLITB / 64) ? wsum[lane] : 0;
#pragma unroll
            for (int d = 1; d < SPLITB / 64; d <<= 1) {
                int x = __shfl_up(s, d);
                if (lane >= d) s += x;
            }
            if (lane < SPLITB / 64) wsum[lane] = s;
        }
        __syncthreads();
        const int excl = (incl - v) + (wid ? wsum[wid - 1] : 0);
        bbase[t * NPART + p] = excl;
        if (t == SPLITB - 1) total[p] = excl + v;
        __syncthreads();
    }
    if (t == 0) {
        int run = 0;
        for (int p = 0; p < NPART; ++p) { pb[p] = run; run += total[p]; }
        pb[NPART] = run;
        for (int p = 0; p <= NPART; ++p) pbase[p] = pb[p];
    }
    __syncthreads();
    for (int p = 0; p < NPART; ++p)
        bbase[t * NPART + p] += pb[p];
}

// ---------------------------------------------------------------------------
// k_split: ONE pass, ZERO global atomics. LDS cursors seeded from bbase.
// ---------------------------------------------------------------------------
__global__ __launch_bounds__(256) void k_split(
    const int* __restrict__ ei, const float* __restrict__ nr, const float* __restrict__ ni,
    const int* __restrict__ bbase, u32* __restrict__ ssrc, u64* __restrict__ smrec,
    int n_edges, int slice, int chunk)
{
    __shared__ int cnt[NPART];
    __shared__ int gb[NPART];
    __shared__ int lcur[NPART];
    const int t = threadIdx.x;
    if (t < NPART) lcur[t] = bbase[blockIdx.x * NPART + t];
    const int cbeg = blockIdx.x * chunk;
    const int cend = min(cbeg + chunk, n_edges);

    for (int base = cbeg; base < cend; base += 256 * SITEMS) {
        if (t < NPART) cnt[t] = 0;
        __syncthreads();
        int p[SITEMS], lpos[SITEMS];
        u32 s[SITEMS]; u64 mrec[SITEMS];
#pragma unroll
        for (int j = 0; j < SITEMS; ++j) {
            const int e = base + t + 256 * j;
            if (e < cend) {
                s[j] = (u32)ei[e];
                const u32 d = (u32)ei[n_edges + e];
                const u32 nn = pack_bf16x2(nr[e], ni[e]);
                mrec[j] = (u64)d | ((u64)nn << 32);
                p[j] = (int)(s[j] / (u32)slice);
                lpos[j] = atomicAdd(&cnt[p[j]], 1);
            } else p[j] = -1;
        }
        __syncthreads();
        if (t < NPART) { gb[t] = lcur[t]; lcur[t] += cnt[t]; }
        __syncthreads();
#pragma unroll
        for (int j = 0; j < SITEMS; ++j) {
            if (p[j] >= 0) {
                const int gi = gb[p[j]] + lpos[j];
                ssrc[gi]  = s[j];
                smrec[gi] = mrec[j];
            }
        }
        __syncthreads();
    }
}

// ---------------------------------------------------------------------------
// k_hist8: per (part, grp): LDS histogram of staged src -> priv[grp][node].
// ---------------------------------------------------------------------------
__global__ __launch_bounds__(1024) void k_hist8(
    const u32* __restrict__ ssrc, const int* __restrict__ pbase,
    int* __restrict__ priv, int n_nodes, int slice)
{
    __shared__ int h[SLICE_MAX];
    const int p = blockIdx.x & (NPART - 1);
    const int g = blockIdx.x >> 3;
    const int t = threadIdx.x;

    const int lo = p * slice;
    const int hi = min(lo + slice, n_nodes);
    const int sl = hi - lo;
    if (sl <= 0) return;

    for (int i = t; i < sl; i += 1024) h[i] = 0;
    __syncthreads();

    const int pb = pbase[p], pe = pbase[p + 1];
    const long long len = pe - pb;
    const int beg = pb + (int)(len * g / EGRP);
    const int end = pb + (int)(len * (g + 1) / EGRP);
    for (int e = beg + t; e < end; e += 1024)
        atomicAdd(&h[(int)ssrc[e] - lo], 1);
    __syncthreads();

    int* __restrict__ dst = priv + (size_t)g * n_nodes + lo;
    for (int i = t; i < sl; i += 1024) dst[i] = h[i];
}

// ---------------------------------------------------------------------------
// Scan pass 1.
// ---------------------------------------------------------------------------
__global__ __launch_bounds__(1024) void k_scan1(
    const int* __restrict__ priv, int* __restrict__ pre,
    int* __restrict__ partials, int n, int n_nodes)
{
    __shared__ int wsum[16];
    const int t = threadIdx.x;
    const int lane = t & 63, wid = t >> 6;
    const int base = blockIdx.x * (SCAN_BLOCK * SCAN_ITEMS) + t * SCAN_ITEMS;

    int v[SCAN_ITEMS];
    int local = 0;
#pragma unroll
    for (int j = 0; j < SCAN_ITEMS; ++j) {
        const int idx = base + j;
        int c = 0;
        if (idx < n) {
            for (int g = 0; g < EGRP; ++g) c += priv[(size_t)g * n_nodes + idx];
        }
        v[j] = local;
        local += c;
    }
    int incl = local;
#pragma unroll
    for (int d = 1; d < 64; d <<= 1) {
        int x = __shfl_up(incl, d);
        if (lane >= d) incl += x;
    }
    if (lane == 63) wsum[wid] = incl;
    __syncthreads();
    if (wid == 0) {
        int s = (lane < 16) ? wsum[lane] : 0;
#pragma unroll
        for (int d = 1; d < 16; d <<= 1) {
            int x = __shfl_up(s, d);
            if (lane >= d) s += x;
        }
        if (lane < 16) wsum[lane] = s;
    }
    __syncthreads();
    const int texcl = (incl - local) + (wid ? wsum[wid - 1] : 0);
#pragma unroll
    for (int j = 0; j < SCAN_ITEMS; ++j) {
        const int idx = base + j;
        if (idx < n) pre[idx] = texcl + v[j];
    }
    if (t == SCAN_BLOCK - 1) partials[blockIdx.x] = texcl + local;
}

// Pass 2: final offsets + per-grp sub-offsets IN-PLACE over priv.
__global__ __launch_bounds__(1024) void k_scan2(
    int* __restrict__ pre, const int* __restrict__ partials,
    int* __restrict__ po, int n, int n_nodes, int n_edges)
{
    __shared__ int s_off;
    const int t = threadIdx.x;
    if (t < 64) {
        int val = (t < blockIdx.x) ? partials[t] : 0;
#pragma unroll
        for (int d = 32; d > 0; d >>= 1) val += __shfl_down(val, d);
        if (t == 0) s_off = val;
    }
    __syncthreads();
    const int boff = s_off;
    const int base = blockIdx.x * (SCAN_BLOCK * SCAN_ITEMS) + t * SCAN_ITEMS;
#pragma unroll
    for (int j = 0; j < SCAN_ITEMS; ++j) {
        const int idx = base + j;
        if (idx < n) {
            const int o = boff + pre[idx];
            pre[idx] = o;
            int running = o;
            for (int g = 0; g < EGRP; ++g) {
                const size_t ix = (size_t)g * n_nodes + idx;
                const int c = po[ix];
                po[ix] = running;
                running += c;
            }
        }
    }
    if (blockIdx.x == 0 && t == 0) pre[n] = n_edges;
}

// ---------------------------------------------------------------------------
// k_place3: LDS cursors seeded from off2; partition-local staged reads.
// ---------------------------------------------------------------------------
__global__ __launch_bounds__(1024) void k_place3(
    const u32* __restrict__ ssrc, const u64* __restrict__ smrec,
    const int* __restrict__ pbase, const int* __restrict__ off2,
    u64* __restrict__ meta2, int n_nodes, int slice)
{
    __shared__ int cur[SLICE_MAX];
    const int p = blockIdx.x & (NPART - 1);
    const int g = blockIdx.x >> 3;
    const int t = threadIdx.x;

    const int lo = p * slice;
    const int hi = min(lo + slice, n_nodes);
    const int sl = hi - lo;
    if (sl <= 0) return;

    const int* __restrict__ o2 = off2 + (size_t)g * n_nodes + lo;
    for (int i = t; i < sl; i += 1024) cur[i] = o2[i];
    __syncthreads();

    const int pb = pbase[p], pe = pbase[p + 1];
    const long long len = pe - pb;
    const int beg = pb + (int)(len * g / EGRP);
    const int end = pb + (int)(len * (g + 1) / EGRP);
    for (int e = beg + t; e < end; e += 1024) {
        const int s = (int)ssrc[e];
        const int pos = atomicAdd(&cur[s - lo], 1);
        meta2[pos] = smrec[e];
    }
}

// ---------------------------------------------------------------------------
// Gather: partitioned; nt loads for one-touch streams (meta2, initp).
// ---------------------------------------------------------------------------
#define APPLY2(m, p, aR, aI)                                  \
    do {                                                      \
        const u32 nnv = (u32)((m) >> 32);                     \
        const float cr = unpack_lo(nnv);                      \
        const float ci = unpack_hi(nnv);                      \
        const float xr = unpack_lo(p);                        \
        const float xi = unpack_hi(p);                        \
        aR = fmaf(cr, xr, fmaf(-ci, xi, aR));                 \
        aI = fmaf(cr, xi, fmaf(ci, xr, aI));                  \
    } while (0)

__global__ __launch_bounds__(256) void k_gather(
    const u32* __restrict__ x1p, const u32* __restrict__ initp,
    const int* __restrict__ offsets, const u64* __restrict__ meta2,
    float* __restrict__ out_real, float* __restrict__ out_imag,
    int n_nodes, int slice)
{
    const int part = blockIdx.x & (NPART - 1);
    const int lane = threadIdx.x & 63;
    const int wip = ((blockIdx.x >> 3) << 2) + (threadIdx.x >> 6);
    const int wpp = (gridDim.x >> 3) << 2;

    const int lo = part * slice;
    const int hi = min(lo + slice, n_nodes);
    if (hi <= lo) return;
    const int chunk = (hi - lo + wpp - 1) / wpp;
    const int nbeg = lo + wip * chunk;
    const int nend = min(nbeg + chunk, hi);

    for (int n = nbeg; n < nend; ++n) {
        const int nu = __builtin_amdgcn_readfirstlane(n);
        const int beg = __builtin_amdgcn_readfirstlane(offsets[nu]);
        const int end = __builtin_amdgcn_readfirstlane(offsets[nu + 1]);

        float aR0 = 0.f, aI0 = 0.f, aR1 = 0.f, aI1 = 0.f;
        float aR2 = 0.f, aI2 = 0.f, aR3 = 0.f, aI3 = 0.f;

        int e = beg;
        for (; e + 8 <= end; e += 8) {
            const u64 m0 = __builtin_nontemporal_load(meta2 + e + 0);
            const u64 m1 = __builtin_nontemporal_load(meta2 + e + 1);
            const u64 m2 = __builtin_nontemporal_load(meta2 + e + 2);
            const u64 m3 = __builtin_nontemporal_load(meta2 + e + 3);
            const u64 m4 = __builtin_nontemporal_load(meta2 + e + 4);
            const u64 m5 = __builtin_nontemporal_load(meta2 + e + 5);
            const u64 m6 = __builtin_nontemporal_load(meta2 + e + 6);
            const u64 m7 = __builtin_nontemporal_load(meta2 + e + 7);
            const u32 p0 = x1p[(size_t)(u32)m0 * F + lane];
            const u32 p1 = x1p[(size_t)(u32)m1 * F + lane];
            const u32 p2 = x1p[(size_t)(u32)m2 * F + lane];
            const u32 p3 = x1p[(size_t)(u32)m3 * F + lane];
            const u32 p4 = x1p[(size_t)(u32)m4 * F + lane];
            const u32 p5 = x1p[(size_t)(u32)m5 * F + lane];
            const u32 p6 = x1p[(size_t)(u32)m6 * F + lane];
            const u32 p7 = x1p[(size_t)(u32)m7 * F + lane];
            APPLY2(m0, p0, aR0, aI0);
            APPLY2(m1, p1, aR1, aI1);
            APPLY2(m2, p2, aR2, aI2);
            APPLY2(m3, p3, aR3, aI3);
            APPLY2(m4, p4, aR0, aI0);
            APPLY2(m5, p5, aR1, aI1);
            APPLY2(m6, p6, aR2, aI2);
            APPLY2(m7, p7, aR3, aI3);
        }
        for (; e + 4 <= end; e += 4) {
            const u64 m0 = __builtin_nontemporal_load(meta2 + e + 0);
            const u64 m1 = __builtin_nontemporal_load(meta2 + e + 1);
            const u64 m2 = __builtin_nontemporal_load(meta2 + e + 2);
            const u64 m3 = __builtin_nontemporal_load(meta2 + e + 3);
            const u32 p0 = x1p[(size_t)(u32)m0 * F + lane];
            const u32 p1 = x1p[(size_t)(u32)m1 * F + lane];
            const u32 p2 = x1p[(size_t)(u32)m2 * F + lane];
            const u32 p3 = x1p[(size_t)(u32)m3 * F + lane];
            APPLY2(m0, p0, aR0, aI0);
            APPLY2(m1, p1, aR1, aI1);
            APPLY2(m2, p2, aR2, aI2);
            APPLY2(m3, p3, aR3, aI3);
        }
        for (; e < end; ++e) {
            const u64 m = __builtin_nontemporal_load(meta2 + e);
            const u32 p = x1p[(size_t)(u32)m * F + lane];
            APPLY2(m, p, aR0, aI0);
        }

        const size_t b = (size_t)nu * F + lane;
        const u32 iw = __builtin_nontemporal_load(initp + b); // aliases out_real[b]
        const float oR = unpack_lo(iw) + ((aR0 + aR1) + (aR2 + aR3));
        const float oI = unpack_hi(iw) + ((aI0 + aI1) + (aI2 + aI3));
        __builtin_nontemporal_store(oR, &out_real[b]);
        __builtin_nontemporal_store(oI, &out_imag[b]);
    }
}

// ---------------------------------------------------------------------------
// Fallback (ws too small or slice too big): f32 init + atomic scatter.
// ---------------------------------------------------------------------------
__global__ __launch_bounds__(256) void k_init_out(
    const float* __restrict__ x_real, const float* __restrict__ x_imag,
    const float* __restrict__ weight, const float* __restrict__ bias,
    float* __restrict__ out_real, float* __restrict__ out_imag, int n_nodes)
{
    const int lane = threadIdx.x & 63;
    const int waveId = (blockIdx.x * blockDim.x + threadIdx.x) >> 6;
    const int nWaves = (gridDim.x * blockDim.x) >> 6;
    const float* __restrict__ W0 = weight;
    float w0c[F];
#pragma unroll
    for (int k = 0; k < F; ++k) w0c[k] = W0[k * F + lane];
    const float bf = bias[lane];
    for (int n = waveId; n < n_nodes; n += nWaves) {
        const int nu = __builtin_amdgcn_readfirstlane(n);
        const float4* __restrict__ xr4 = (const float4*)(x_real + (size_t)nu * F);
        const float4* __restrict__ xi4 = (const float4*)(x_imag + (size_t)nu * F);
        float gR = 0.f, gI = 0.f;
#pragma unroll
        for (int k4 = 0; k4 < F / 4; ++k4) {
            const float4 vr = xr4[k4];
            const float4 vi = xi4[k4];
            const float xr[4] = {vr.x, vr.y, vr.z, vr.w};
            const float xi[4] = {vi.x, vi.y, vi.z, vi.w};
#pragma unroll
            for (int j = 0; j < 4; ++j) {
                const int k = 4 * k4 + j;
                gR = fmaf(xr[j], w0c[k], gR);
                gI = fmaf(xi[j], w0c[k], gI);
            }
        }
        const size_t b = (size_t)nu * F + lane;
        out_real[b] = gR + bf;
        out_imag[b] = gI + bf;
    }
}

__global__ __launch_bounds__(256) void k_x1_only(
    const float* __restrict__ x_real, const float* __restrict__ x_imag,
    const float* __restrict__ weight, u32* __restrict__ x1p, int n_nodes)
{
    const int lane = threadIdx.x & 63;
    const int waveId = (blockIdx.x * blockDim.x + threadIdx.x) >> 6;
    const int nWaves = (gridDim.x * blockDim.x) >> 6;
    const float* __restrict__ W1 = weight + F * F;
    float w1c[F];
#pragma unroll
    for (int k = 0; k < F; ++k) w1c[k] = W1[k * F + lane];
    for (int n = waveId; n < n_nodes; n += nWaves) {
        const int nu = __builtin_amdgcn_readfirstlane(n);
        const float4* __restrict__ xr4 = (const float4*)(x_real + (size_t)nu * F);
        const float4* __restrict__ xi4 = (const float4*)(x_imag + (size_t)nu * F);
        float aR = 0.f, aI = 0.f;
#pragma unroll
        for (int k4 = 0; k4 < F / 4; ++k4) {
            const float4 vr = xr4[k4];
            const float4 vi = xi4[k4];
            const float xr[4] = {vr.x, vr.y, vr.z, vr.w};
            const float xi[4] = {vi.x, vi.y, vi.z, vi.w};
#pragma unroll
            for (int j = 0; j < 4; ++j) {
                const int k = 4 * k4 + j;
                aR = fmaf(xr[j], w1c[k], aR);
                aI = fmaf(xi[j], w1c[k], aI);
            }
        }
        x1p[(size_t)nu * F + lane] = pack_bf16x2(aR, aI);
    }
}

__global__ __launch_bounds__(256) void k_scatter(
    const u32* __restrict__ x1p, const int* __restrict__ edge_index,
    const float* __restrict__ norm_real, const float* __restrict__ norm_imag,
    float* __restrict__ out_real, float* __restrict__ out_imag, int n_edges)
{
    const long long gid = (long long)blockIdx.x * blockDim.x + threadIdx.x;
    const long long total = (long long)n_edges * 16;
    if (gid >= total) return;
    const int e = (int)(gid >> 4);
    const int c = (int)(gid & 15);
    const int s = edge_index[e];
    const int d = edge_index[n_edges + e];
    const float cr = norm_real[e];
    const float ci = norm_imag[e];
    const uint4 p4 = *(const uint4*)(x1p + (size_t)d * F + c * 4);
    const u32 pp[4] = {p4.x, p4.y, p4.z, p4.w};
    float* __restrict__ pr = out_real + (size_t)s * F + c * 4;
    float* __restrict__ pi = out_imag + (size_t)s * F + c * 4;
#pragma unroll
    for (int j = 0; j < 4; ++j) {
        const float xr = unpack_lo(pp[j]);
        const float xi = unpack_hi(pp[j]);
        unsafeAtomicAdd(pr + j, fmaf(cr, xr, -ci * xi));
        unsafeAtomicAdd(pi + j, fmaf(cr, xi, ci * xr));
    }
}

extern "C" void kernel_launch(void* const* d_in, const int* in_sizes, int n_in,
                              void* d_out, int out_size, void* d_ws, size_t ws_size,
                              hipStream_t stream) {
    const float* x_real     = (const float*)d_in[0];
    const float* x_imag     = (const float*)d_in[1];
    const float* weight     = (const float*)d_in[2];
    const float* bias       = (const float*)d_in[3];
    const float* norm_real  = (const float*)d_in[4];
    const float* norm_imag  = (const float*)d_in[5];
    const int*   edge_index = (const int*)d_in[6];

    const int n_nodes = in_sizes[0] / F;
    const int n_edges = in_sizes[4];
    const int slice   = (n_nodes + NPART - 1) / NPART;

    float* out_real = (float*)d_out;
    float* out_imag = out_real + (size_t)n_nodes * F;
    u32*   initp    = (u32*)d_out;   // packed bf16 init, overwritten by gather

    // ws layout:
    //   region A: staged ssrc(E*4)+smrec(E*8) during CSR build, then x1p
    //   [meta2][offsets][priv(=off2)][partials][bcnt][bbase][pbase]
    char* ws = (char*)d_ws;
    const size_t x1_bytes     = (size_t)n_nodes * F * sizeof(u32);
    const size_t staged_bytes = (size_t)n_edges * 12;
    const size_t A_bytes      = (x1_bytes > staged_bytes ? x1_bytes : staged_bytes + 8);
    const size_t meta_bytes   = (size_t)n_edges * sizeof(u64);
    const size_t off_bytes    = (size_t)(n_nodes + 1) * sizeof(int);
    const size_t priv_bytes   = (size_t)EGRP * n_nodes * sizeof(int);
    const size_t par_bytes    = 64 * sizeof(int);
    const size_t bcnt_bytes   = (size_t)SPLITB * NPART * sizeof(int);
    const size_t bbase_bytes  = (size_t)SPLITB * NPART * sizeof(int);
    const size_t pbase_bytes  = (NPART + 1) * sizeof(int);
    const size_t need = A_bytes + meta_bytes + off_bytes + priv_bytes + par_bytes
                      + bcnt_bytes + bbase_bytes + pbase_bytes;

    u32* x1p      = (u32*)ws;
    u32* ssrc     = (u32*)ws;
    u64* smrec    = (u64*)(ws + (size_t)n_edges * sizeof(u32));
    u64* meta2    = (u64*)(ws + A_bytes);
    int* offsets  = (int*)(ws + A_bytes + meta_bytes);
    int* priv     = (int*)(ws + A_bytes + meta_bytes + off_bytes);
    int* partials = (int*)(ws + A_bytes + meta_bytes + off_bytes + priv_bytes);
    int* bcnt     = partials + 64;
    int* bbase    = bcnt + SPLITB * NPART;
    int* pbase    = bbase + SPLITB * NPART;

    if (ws_size >= need && slice <= SLICE_MAX) {
        const int schunk = (n_edges + SPLITB - 1) / SPLITB;
        // --- CSR build: deterministic single-pass split, zero global atomics ---
        k_coarse<<<SPLITB, 256, 0, stream>>>(edge_index, bcnt, n_edges, slice, schunk);
        k_base2<<<1, SPLITB, 0, stream>>>(bcnt, bbase, pbase);
        k_split<<<SPLITB, 256, 0, stream>>>(edge_index, norm_real, norm_imag,
                                            bbase, ssrc, smrec, n_edges, slice, schunk);
        k_hist8<<<NPART * EGRP, 1024, 0, stream>>>(ssrc, pbase, priv, n_nodes, slice);
        const int sblocks = (n_nodes + SCAN_BLOCK * SCAN_ITEMS - 1) / (SCAN_BLOCK * SCAN_ITEMS);
        k_scan1<<<sblocks, SCAN_BLOCK, 0, stream>>>(priv, offsets, partials, n_nodes, n_nodes);
        k_scan2<<<sblocks, SCAN_BLOCK, 0, stream>>>(offsets, partials, priv,
                                                    n_nodes, n_nodes, n_edges);
        k_place3<<<NPART * EGRP, 1024, 0, stream>>>(ssrc, smrec, pbase, priv,
                                                    meta2, n_nodes, slice);
        // --- dense init via MFMA (x1p overwrites staging) + gather ---
        const int gblocks = (n_nodes + 63) / 64;
        k_gemm<<<gblocks, 256, 0, stream>>>(
            x_real, x_imag, weight, bias, x1p, initp, n_nodes);
        k_gather<<<2048, 256, 0, stream>>>(
            x1p, initp, offsets, meta2, out_real, out_imag, n_nodes, slice);
    } else {
        k_init_out<<<2048, 256, 0, stream>>>(
            x_real, x_imag, weight, bias, out_real, out_imag, n_nodes);
        k_x1_only<<<2048, 256, 0, stream>>>(x_real, x_imag, weight, x1p, n_nodes);
        const long long work = (long long)n_edges * 16;
        const int blocks = (int)((work + 255) / 256);
        k_scatter<<<blocks, 256, 0, stream>>>(
            x1p, edge_index, norm_real, norm_imag, out_real, out_imag, n_edges);
    }
}